// Round 1
// baseline (1512.377 us; speedup 1.0000x reference)
//
#include <hip/hip_runtime.h>
#include <math.h>

#define NPTS 1024
#define LMK 50
#define NPAIRS 1225       // 50*49/2
#define KMED 599          // global median index 1249 -> pairs-only index (1249-50)/2 = 599
#define PPT 20            // ceil(1225/64)
#define CAND_CAP 320

__device__ __forceinline__ unsigned monof(float f) {
  unsigned u = __float_as_uint(f);
  return (u & 0x80000000u) ? ~u : (u | 0x80000000u);
}
__device__ __forceinline__ float unmono(unsigned m) {
  unsigned b = (m & 0x80000000u) ? (m & 0x7FFFFFFFu) : ~m;
  return __uint_as_float(b);
}
__device__ __forceinline__ int wsumi(int v) {
#pragma unroll
  for (int j = 32; j; j >>= 1) v += __shfl_xor(v, j, 64);
  return v;
}
__device__ __forceinline__ float wsumf(float v) {
#pragma unroll
  for (int j = 32; j; j >>= 1) v += __shfl_xor(v, j, 64);
  return v;
}
__device__ __forceinline__ unsigned wminu(unsigned v) {
#pragma unroll
  for (int j = 32; j; j >>= 1) { unsigned o = __shfl_xor(v, j, 64); v = o < v ? o : v; }
  return v;
}
__device__ __forceinline__ unsigned wmaxu(unsigned v) {
#pragma unroll
  for (int j = 32; j; j >>= 1) { unsigned o = __shfl_xor(v, j, 64); v = o > v ? o : v; }
  return v;
}
// ascending bitonic sort of one u32 per lane across the 64-lane wave
__device__ __forceinline__ unsigned bitonic_asc(unsigned v, int lane) {
#pragma unroll
  for (int k = 2; k <= 64; k <<= 1) {
#pragma unroll
    for (int j = k >> 1; j > 0; j >>= 1) {
      unsigned o = __shfl_xor(v, j, 64);
      bool up  = ((lane & k) == 0);
      bool low = ((lane & j) == 0);
      unsigned mn = v < o ? v : o;
      unsigned mx = v < o ? o : v;
      v = (up == low) ? mn : mx;
    }
  }
  return v;
}

__global__ __launch_bounds__(64)
void ph_kernel(const float* __restrict__ pc,
               const float* __restrict__ aw,
               const float* __restrict__ abp,
               const float* __restrict__ fwp,
               const float* __restrict__ dbp,
               float* __restrict__ out)
{
  __shared__ __align__(16) float s_pts[NPTS * 2];     // 8 KB
  __shared__ unsigned long long s_cand[CAND_CAP];     // 2.5 KB
  __shared__ float s_lm[LMK * 2];
  __shared__ unsigned s_band[64];

  const int lane = threadIdx.x;
  const int b = blockIdx.x;
  const float aw0 = aw[0], aw1 = aw[1], ab = abp[0];
  const float afw = fabsf(fwp[0]);
  const float dbv = dbp[0];

  // ---- Phase 1: load 1024 points (float4 coalesced), score -> monotone u32 keys
  const float4* src = (const float4*)(pc + (size_t)b * (NPTS * 2));
  unsigned key[16];
#pragma unroll
  for (int k4 = 0; k4 < 8; ++k4) {
    int f = lane + 64 * k4;
    float4 q = src[f];
    ((float4*)s_pts)[f] = q;
    float s0 = __fadd_rn(__fadd_rn(__fmul_rn(q.x, aw0), __fmul_rn(q.y, aw1)), ab);
    float s1 = __fadd_rn(__fadd_rn(__fmul_rn(q.z, aw0), __fmul_rn(q.w, aw1)), ab);
    key[2 * k4]     = monof(s0);
    key[2 * k4 + 1] = monof(s1);
  }
  __syncthreads();

  // ---- Phase 2: exact top-50 landmark selection
  // seed threshold from a 64-sample sorted order statistic
  unsigned sortedk = bitonic_asc(key[0], lane);
  unsigned T = __shfl(sortedk, 61, 64);
  unsigned long long lo = 0, hi = 1ull << 32;
  unsigned cLo = NPTS;                       // count(key >= lo=0) = all
#pragma unroll 1
  for (int it = 0; it < 36; ++it) {
    int mc = 0;
#pragma unroll
    for (int k = 0; k < 16; ++k) mc += (key[k] >= T) ? 1 : 0;
    int cnt = wsumi(mc);
    if (cnt >= LMK) { lo = T; cLo = (unsigned)cnt; } else { hi = T; }
    if (cLo <= 80u || (hi - lo) <= 1ull) break;
    T = (unsigned)((lo + hi) >> 1);
  }
  unsigned Tl = (unsigned)lo;
  int C = (cLo < CAND_CAP) ? (int)cLo : CAND_CAP;

  // compact candidates (key >= Tl) as packed 42-bit unique keys: (key<<10)|(1023-idx)
  unsigned long long ltmask = (1ull << lane) - 1ull;
  unsigned base = 0;
#pragma unroll
  for (int k = 0; k < 16; ++k) {
    bool pred = (key[k] >= Tl);
    unsigned long long m = __ballot(pred);
    unsigned pos = base + (unsigned)__popcll(m & ltmask);
    if (pred && pos < CAND_CAP) {
      int idx = 2 * (lane + 64 * (k >> 1)) + (k & 1);
      s_cand[pos] = (((unsigned long long)key[k]) << 10) | (unsigned)(1023 - idx);
    }
    base += (unsigned)__popcll(m);
  }
  __syncthreads();

  // exact rank (score desc, index asc): selected ranks are exactly 0..49
  for (int c = lane; c < C; c += 64) {
    unsigned long long pk = s_cand[c];
    int rank = 0;
    for (int o = 0; o < C; ++o) rank += (s_cand[o] > pk) ? 1 : 0;
    if (rank < LMK) {
      int idx = 1023 - (int)(pk & 1023ull);
      s_lm[2 * rank]     = s_pts[2 * idx];
      s_lm[2 * rank + 1] = s_pts[2 * idx + 1];
    }
  }
  __syncthreads();

  // ---- Phase 3: upper-triangle pairwise scaled distances, kept in registers (mono u32)
  unsigned mvals[PPT];
  float lsum = 0.0f;
  unsigned lmin = 0xFFFFFFFFu, lmax = 0u;
#pragma unroll
  for (int k = 0; k < PPT; ++k) {
    int p = lane + 64 * k;
    mvals[k] = 0u;
    if (p < NPAIRS) {
      // map linear pair p -> (i, j), i<j, off(i) = i*(99-i)/2
      float fp = (float)p;
      int i = (int)((99.0f - sqrtf(9801.0f - 8.0f * fp)) * 0.5f);
      if (i < 0) i = 0;
      if (i > 48) i = 48;
      while (i > 0 && (i * (99 - i)) / 2 > p) --i;
      while (((i + 1) * (98 - i)) / 2 <= p) ++i;
      int j = i + 1 + (p - (i * (99 - i)) / 2);
      float dx = s_lm[2 * i]     - s_lm[2 * j];
      float dy = s_lm[2 * i + 1] - s_lm[2 * j + 1];
      float d2 = __fadd_rn(__fmul_rn(dx, dx), __fmul_rn(dy, dy));
      float d = (d2 > 0.0f) ? sqrtf(d2) : 0.0f;
      float v = __fadd_rn(__fmul_rn(d, afw), dbv);
      unsigned mv = monof(v);
      mvals[k] = mv;
      lsum += 2.0f * v;                       // symmetric: counts twice
      lmin = mv < lmin ? mv : lmin;
      lmax = mv > lmax ? mv : lmax;
    }
  }
  unsigned mdb = monof(dbv);
  if (lane == 0) {                            // 50 diagonal entries == dbv
    lsum += (float)LMK * dbv;
    lmin = mdb < lmin ? mdb : lmin;
    lmax = mdb > lmax ? mdb : lmax;
  }
  float total = wsumf(lsum);
  unsigned gmin = wminu(lmin);
  unsigned gmax = wmaxu(lmax);
  float mean = total / 2500.0f;

  // two-pass variance (ddof=1)
  float ls2 = 0.0f;
#pragma unroll
  for (int k = 0; k < PPT; ++k) {
    int p = lane + 64 * k;
    if (p < NPAIRS) {
      float v = unmono(mvals[k]);
      float dd = v - mean;
      ls2 += 2.0f * dd * dd;
    }
  }
  if (lane == 0) { float dd = dbv - mean; ls2 += (float)LMK * dd * dd; }
  float s2 = wsumf(ls2);
  float stdv = sqrtf(s2 / 2499.0f);

  // ---- Phase 4: exact median = 599-th smallest of the 1225 pair values
  unsigned long long mlo = 0, mhi = 1ull << 32;
  int cntLo = 0, cntHi = NPAIRS;              // cntLT(mlo)=0 <= 599 < cntLT(mhi)=1225
  unsigned med_u;
#pragma unroll 1
  for (int it = 0; it < 40; ++it) {
    if ((unsigned)(cntHi - cntLo) <= 64u || (mhi - mlo) <= 1ull) break;
    unsigned T2 = (unsigned)((mlo + mhi) >> 1);
    int mc = 0;
#pragma unroll
    for (int k = 0; k < PPT; ++k) {
      int p = lane + 64 * k;
      mc += (p < NPAIRS && mvals[k] < T2) ? 1 : 0;
    }
    int c = wsumi(mc);
    if (c <= KMED) { mlo = T2; cntLo = c; } else { mhi = T2; cntHi = c; }
  }
  if ((mhi - mlo) <= 1ull && (unsigned)(cntHi - cntLo) > 64u) {
    med_u = (unsigned)mlo;                    // massive ties at value mlo
  } else {
    // compact band [mlo, mhi) (<=64 values) and wave-sort it
    unsigned Tlo2 = (unsigned)mlo;
    unsigned base2 = 0;
#pragma unroll
    for (int k = 0; k < PPT; ++k) {
      int p = lane + 64 * k;
      bool pred = (p < NPAIRS) && (mvals[k] >= Tlo2) && ((unsigned long long)mvals[k] < mhi);
      unsigned long long m = __ballot(pred);
      unsigned pos = base2 + (unsigned)__popcll(m & ltmask);
      if (pred && pos < 64u) s_band[pos] = mvals[k];
      base2 += (unsigned)__popcll(m);
    }
    __syncthreads();
    int Bn = (int)base2;
    unsigned v = (lane < Bn) ? s_band[lane] : 0xFFFFFFFFu;
    v = bitonic_asc(v, lane);
    int tsel = KMED - cntLo;                  // position inside band
    med_u = __shfl(v, tsel, 64);
  }
  float medf = unmono(med_u);
  (void)medf;

  // ---- conn = frac(scaled < med) over all 2500
  int lcc = 0;
#pragma unroll
  for (int k = 0; k < PPT; ++k) {
    int p = lane + 64 * k;
    lcc += (p < NPAIRS && mvals[k] < med_u) ? 2 : 0;
  }
  if (lane == 0) lcc += (mdb < med_u) ? LMK : 0;
  int ccnt = wsumi(lcc);
  float conn = (float)ccnt / 2500.0f;

  // ---- row sums (row-per-lane, deterministic, no atomics) and their std (ddof=1)
  float rsum = 0.0f;
  if (lane < LMK) {
    float xr = s_lm[2 * lane], yr = s_lm[2 * lane + 1];
#pragma unroll 1
    for (int c2 = 0; c2 < LMK; ++c2) {
      float dx = xr - s_lm[2 * c2];
      float dy = yr - s_lm[2 * c2 + 1];
      float d2 = __fadd_rn(__fmul_rn(dx, dx), __fmul_rn(dy, dy));
      float d = (d2 > 0.0f) ? sqrtf(d2) : 0.0f;
      rsum += __fadd_rn(__fmul_rn(d, afw), dbv);
    }
  }
  float rtot = wsumf(rsum);
  float rmean = rtot / (float)LMK;
  float rd = (lane < LMK) ? (rsum - rmean) : 0.0f;
  float rvar = wsumf(rd * rd) / 49.0f;
  float rowstd = sqrtf(rvar);

  if (lane == 0) {
    float* o = out + (size_t)b * 6;
    o[0] = mean;
    o[1] = stdv;
    o[2] = unmono(gmin);
    o[3] = unmono(gmax);
    o[4] = conn;
    o[5] = rowstd;
  }
}

extern "C" void kernel_launch(void* const* d_in, const int* in_sizes, int n_in,
                              void* d_out, int out_size, void* d_ws, size_t ws_size,
                              hipStream_t stream) {
  (void)in_sizes; (void)n_in; (void)d_ws; (void)ws_size;
  const float* pc = (const float*)d_in[0];
  const float* aw = (const float*)d_in[1];
  const float* ab = (const float*)d_in[2];
  const float* fw = (const float*)d_in[3];
  const float* db = (const float*)d_in[4];
  float* out = (float*)d_out;
  int B = out_size / 6;
  ph_kernel<<<B, 64, 0, stream>>>(pc, aw, ab, fw, db, out);
}

// Round 4
// 749.154 us; speedup vs baseline: 2.0188x; 2.0188x over previous
//
#include <hip/hip_runtime.h>
#include <math.h>

#define LMK 50
#define NPAIRS 1225      // 50*49/2
#define KMED 599         // global lower-median index 1249 -> pairs-only rank (1249-50)/2
#define PPT 20           // ceil(1225/64)
#define CAP 128

typedef unsigned long long u64;

__device__ __forceinline__ unsigned monof(float f) {
  unsigned u = __float_as_uint(f);
  return (u & 0x80000000u) ? ~u : (u | 0x80000000u);
}
__device__ __forceinline__ float unmono(unsigned m) {
  unsigned b = (m & 0x80000000u) ? (m & 0x7FFFFFFFu) : ~m;
  return __uint_as_float(b);
}
__device__ __forceinline__ unsigned mbcnt64(u64 m) {
  return __builtin_amdgcn_mbcnt_hi((unsigned)(m >> 32),
         __builtin_amdgcn_mbcnt_lo((unsigned)m, 0u));
}
__device__ __forceinline__ float wsumf(float v) {
#pragma unroll
  for (int j = 32; j; j >>= 1) v += __shfl_xor(v, j, 64);
  return v;
}
__device__ __forceinline__ unsigned wminu(unsigned v) {
#pragma unroll
  for (int j = 32; j; j >>= 1) { unsigned o = __shfl_xor(v, j, 64); v = o < v ? o : v; }
  return v;
}
__device__ __forceinline__ unsigned wmaxu(unsigned v) {
#pragma unroll
  for (int j = 32; j; j >>= 1) { unsigned o = __shfl_xor(v, j, 64); v = o > v ? o : v; }
  return v;
}
__device__ __forceinline__ unsigned bitonic_asc(unsigned v, int lane) {
#pragma unroll
  for (int k = 2; k <= 64; k <<= 1) {
#pragma unroll
    for (int j = k >> 1; j > 0; j >>= 1) {
      unsigned o = __shfl_xor(v, j, 64);
      bool up  = ((lane & k) == 0);
      bool low = ((lane & j) == 0);
      unsigned mn = v < o ? v : o;
      unsigned mx = v < o ? o : v;
      v = (up == low) ? mn : mx;
    }
  }
  return v;
}

__global__ __launch_bounds__(64, 4)
void ph_kernel(const float* __restrict__ pc,
               const float* __restrict__ aw,
               const float* __restrict__ abp,
               const float* __restrict__ fwp,
               const float* __restrict__ dbp,
               float* __restrict__ out)
{
  __shared__ u64    s_cand[CAP + 2];
  __shared__ float2 s_cxy[CAP];
  __shared__ float2 s_lm[LMK];
  __shared__ float  s_row[LMK];
  __shared__ unsigned s_band[64];

  const int lane = threadIdx.x;
  const int b = blockIdx.x;
  const float aw0 = aw[0], aw1 = aw[1], ab = abp[0];
  const float afw = fabsf(fwp[0]);
  const float dbv = dbp[0];

  if (lane < LMK) s_row[lane] = 0.0f;

  // Analytic seed: scores ~ N(ab, ||aw||) for N(0,1) points. z=1.45 -> E[count]=75,
  // P(50<=count<=128) > 99.8%. Correctness never depends on this (fallback below).
  const float sig = __fsqrt_rn(aw0 * aw0 + aw1 * aw1);
  const unsigned Tu = monof(__fadd_rn(ab, 1.45f * sig));

  // ---- Phase 1: load + score + fused candidate compaction (threshold known a priori)
  const float4* src = (const float4*)(pc + (size_t)b * 2048);
  unsigned key[16];
  unsigned cnt = 0;
#pragma unroll
  for (int k4 = 0; k4 < 8; ++k4) {
    float4 q = src[lane + 64 * k4];
    float s0 = __fadd_rn(__fadd_rn(__fmul_rn(q.x, aw0), __fmul_rn(q.y, aw1)), ab);
    float s1 = __fadd_rn(__fadd_rn(__fmul_rn(q.z, aw0), __fmul_rn(q.w, aw1)), ab);
    unsigned k0 = monof(s0), k1 = monof(s1);
    key[2 * k4] = k0; key[2 * k4 + 1] = k1;
    const int idx0 = 2 * (lane + 64 * k4);
    {
      bool pr = (k0 >= Tu);
      u64 m = __ballot(pr);
      unsigned pos = cnt + mbcnt64(m);
      if (pr && pos < CAP) {
        s_cand[pos] = (((u64)k0) << 10) | (unsigned)(1023 - idx0);
        s_cxy[pos] = make_float2(q.x, q.y);
      }
      cnt += (unsigned)__popcll(m);
    }
    {
      bool pr = (k1 >= Tu);
      u64 m = __ballot(pr);
      unsigned pos = cnt + mbcnt64(m);
      if (pr && pos < CAP) {
        s_cand[pos] = (((u64)k1) << 10) | (unsigned)(1023 - (idx0 + 1));
        s_cxy[pos] = make_float2(q.z, q.w);
      }
      cnt += (unsigned)__popcll(m);
    }
  }

  // ---- Rare fallback: seed missed [50, CAP] -> bisection on keys (ballot counting)
  if (cnt < LMK || cnt > CAP) {
    u64 lo = 0, hi = 1ull << 32;
    for (int it = 0; it < 34; ++it) {
      unsigned T = (unsigned)((lo + hi) >> 1);
      unsigned c2 = 0;
#pragma unroll
      for (int k = 0; k < 16; ++k) c2 += (unsigned)__popcll(__ballot(key[k] >= T));
      if (c2 >= LMK) { lo = T; if (c2 <= CAP) break; }
      else hi = T;
      if (hi - lo <= 1ull) break;
    }
    const unsigned Tl = (unsigned)lo;
    const float* rowp = pc + (size_t)b * 2048;
    cnt = 0;
#pragma unroll
    for (int k = 0; k < 16; ++k) {
      bool pr = (key[k] >= Tl);
      u64 m = __ballot(pr);
      unsigned pos = cnt + mbcnt64(m);
      if (pr && pos < CAP) {
        int idx = 2 * (lane + 64 * (k >> 1)) + (k & 1);
        s_cand[pos] = (((u64)key[k]) << 10) | (unsigned)(1023 - idx);
        s_cxy[pos] = make_float2(rowp[2 * idx], rowp[2 * idx + 1]);
      }
      cnt += (unsigned)__popcll(m);
    }
  }
  const unsigned C = cnt < CAP ? cnt : CAP;
  if (lane == 0) s_cand[C] = 0ull;     // pad (0 is never > any real packed key)
  __syncthreads();

  // ---- Rank among candidates; top-50 set written to s_lm (order irrelevant:
  //      every output statistic is permutation-invariant in the landmarks)
  const unsigned Ce = (C + 1) & ~1u;
  for (unsigned c = lane; c < C; c += 64) {
    u64 pk = s_cand[c];
    int rank = 0;
    for (unsigned o = 0; o < Ce; o += 2) {
      u64 a0 = s_cand[o], a1 = s_cand[o + 1];
      rank += (a0 > pk) ? 1 : 0;
      rank += (a1 > pk) ? 1 : 0;
    }
    if (rank < LMK) s_lm[rank] = s_cxy[c];
  }
  __syncthreads();

  // ---- Phase 3: 1225 unique pairs via round-robin mapping; row sums via LDS atomics
  unsigned mvals[PPT];
  float lsum = 0.f, lsq = 0.f;
  unsigned lmin = 0xFFFFFFFFu, lmax = 0u;
#pragma unroll
  for (int k = 0; k < PPT; ++k) {
    const int p = lane + 64 * k;
    unsigned i, mrot;
    if (p >= 1200) { i = (unsigned)(p - 1200); mrot = 25u; }
    else { unsigned q50 = (unsigned)p / 50u; mrot = 1u + q50; i = (unsigned)p - 50u * q50; }
    unsigned j = i + mrot; if (j >= LMK) j -= LMK;
    float2 Li = s_lm[i], Lj = s_lm[j];
    float dx = Li.x - Lj.x, dy = Li.y - Lj.y;
    float d2 = __fadd_rn(__fmul_rn(dx, dx), __fmul_rn(dy, dy));
    float d = (d2 > 0.f) ? __fsqrt_rn(d2) : 0.f;
    float v = __fadd_rn(__fmul_rn(d, afw), dbv);
    unsigned mv = monof(v);
    if (p < NPAIRS) {
      lsum += v;
      lsq = __builtin_fmaf(v, v, lsq);
      lmin = mv < lmin ? mv : lmin;
      lmax = mv > lmax ? mv : lmax;
      atomicAdd(&s_row[i], d);
      atomicAdd(&s_row[j], d);
      mvals[k] = mv;
    } else {
      mvals[k] = 0xFFFFFFFFu;      // above any finite value; never counted below
    }
  }
  __syncthreads();

  // ---- mean / std / min / max (diag = 50 copies of dbv)
  const unsigned mdb = monof(dbv);
  float sumv  = 2.f * wsumf(lsum) + 50.f * dbv;
  float sumsq = 2.f * wsumf(lsq) + 50.f * dbv * dbv;
  float mean = sumv * (1.f / 2500.f);
  float var = (sumsq - 2500.f * mean * mean) * (1.f / 2499.f);
  float stdv = __fsqrt_rn(fmaxf(var, 0.f));
  unsigned gmin = wminu(lmin); gmin = mdb < gmin ? mdb : gmin;
  unsigned gmax = wmaxu(lmax); gmax = mdb > gmax ? mdb : gmax;

  // ---- exact median: 599-th smallest pair value; seeded [gmin, gmax+1], interp first
  u64 mlo = gmin, mhi = (u64)gmax + 1ull;
  unsigned cntLo = 0, cntHi = NPAIRS;
  unsigned med_u;
  int iter = 0;
  while ((cntHi - cntLo) > 64u && (mhi - mlo) > 1ull && iter < 48) {
    u64 T;
    if (iter < 10) {
      float frac = (599.5f - (float)cntLo) / (float)(cntHi - cntLo);
      T = mlo + (u64)(frac * (float)(mhi - mlo));
      if (T <= mlo) T = mlo + 1ull;
      if (T >= mhi) T = mhi - 1ull;
    } else {
      T = (mlo + mhi) >> 1;
    }
    const unsigned Tc = (unsigned)T;
    unsigned c = 0;
#pragma unroll
    for (int k = 0; k < PPT; ++k) c += (unsigned)__popcll(__ballot(mvals[k] < Tc));
    if (c <= KMED) { mlo = T; cntLo = c; } else { mhi = T; cntHi = c; }
    ++iter;
  }
  if ((cntHi - cntLo) > 64u) {
    med_u = (unsigned)mlo;               // window collapsed: massive ties at mlo
  } else {
    const unsigned loC = (unsigned)mlo, hiC = (unsigned)(mhi - 1ull);
    unsigned base2 = 0;
#pragma unroll
    for (int k = 0; k < PPT; ++k) {
      bool pr = (mvals[k] >= loC) && (mvals[k] <= hiC);
      u64 m = __ballot(pr);
      unsigned pos = base2 + mbcnt64(m);
      if (pr && pos < 64u) s_band[pos] = mvals[k];
      base2 += (unsigned)__popcll(m);
    }
    __syncthreads();
    unsigned v = (lane < (int)base2) ? s_band[lane] : 0xFFFFFFFFu;
    v = bitonic_asc(v, lane);
    med_u = __shfl(v, (int)(KMED - cntLo), 64);
  }

  // ---- conn = frac(scaled < med) over all 2500
  unsigned cc = 0;
#pragma unroll
  for (int k = 0; k < PPT; ++k) cc += (unsigned)__popcll(__ballot(mvals[k] < med_u));
  unsigned ctot = 2u * cc + ((mdb < med_u) ? 50u : 0u);
  float conn = (float)ctot * (1.f / 2500.f);

  // ---- row-sum std: row_sum_r = afw * D_r + 50*dbv  ->  std = afw * std(D)
  float D = (lane < LMK) ? s_row[lane] : 0.f;
  float sD  = wsumf(D);
  float sD2 = wsumf(D * D);
  float mD = sD * (1.f / 50.f);
  float vD = (sD2 - 50.f * mD * mD) * (1.f / 49.f);
  float rowstd = afw * __fsqrt_rn(fmaxf(vD, 0.f));

  if (lane == 0) {
    float2* o = (float2*)(out + (size_t)b * 6);
    o[0] = make_float2(mean, stdv);
    o[1] = make_float2(unmono(gmin), unmono(gmax));
    o[2] = make_float2(conn, rowstd);
  }
}

extern "C" void kernel_launch(void* const* d_in, const int* in_sizes, int n_in,
                              void* d_out, int out_size, void* d_ws, size_t ws_size,
                              hipStream_t stream) {
  (void)in_sizes; (void)n_in; (void)d_ws; (void)ws_size;
  const float* pc = (const float*)d_in[0];
  const float* aw = (const float*)d_in[1];
  const float* ab = (const float*)d_in[2];
  const float* fw = (const float*)d_in[3];
  const float* db = (const float*)d_in[4];
  float* out = (float*)d_out;
  int B = out_size / 6;
  ph_kernel<<<B, 64, 0, stream>>>(pc, aw, ab, fw, db, out);
}